// Round 1
// baseline (5515.590 us; speedup 1.0000x reference)
//
#include <hip/hip_runtime.h>
#include <math.h>

#ifndef M_PI
#define M_PI 3.14159265358979323846
#endif

#define MATS 8
#define BLK 192           // MATS*24
#define NMATS 38400
#define NGROUPS 1536
#define LROW 588          // buffer stride in floats (576 + 12 for bank stagger)

static_assert(BLK == MATS * 24, "block = MATS*24");

struct Coefs { float c[32]; };

// ---------- row helpers ----------
__device__ __forceinline__ void ldrow24(const float* p, float* r) {
  const float4* q = (const float4*)p;
#pragma unroll
  for (int i = 0; i < 6; ++i) {
    float4 v = q[i];
    r[4*i+0] = v.x; r[4*i+1] = v.y; r[4*i+2] = v.z; r[4*i+3] = v.w;
  }
}
__device__ __forceinline__ void strow24(float* p, const float* r) {
  float4* q = (float4*)p;
#pragma unroll
  for (int i = 0; i < 6; ++i)
    q[i] = make_float4(r[4*i+0], r[4*i+1], r[4*i+2], r[4*i+3]);
}

// acc[j] += sum_k arow[k] * B[k*24+j]   (B in LDS, rows broadcast)
__device__ __forceinline__ void mm24(const float* arow, const float* B, float* acc) {
#pragma unroll
  for (int k = 0; k < 24; ++k) {
    float b[24];
    ldrow24(B + k*24, b);
    float a = arow[k];
#pragma unroll
    for (int j = 0; j < 24; ++j) acc[j] += a * b[j];
  }
}
// two A-rows against the same B (shares the LDS row loads)
__device__ __forceinline__ void mm24_dual(const float* a1, const float* a2,
                                          const float* B, float* acc1, float* acc2) {
#pragma unroll
  for (int k = 0; k < 24; ++k) {
    float b[24];
    ldrow24(B + k*24, b);
    float s1 = a1[k], s2 = a2[k];
#pragma unroll
    for (int j = 0; j < 24; ++j) { acc1[j] += s1 * b[j]; acc2[j] += s2 * b[j]; }
  }
}

// ---------- K1: logm via degree-27 Chebyshev->monomial, Paterson-Stockmeyer k=4 ----------
__global__ __launch_bounds__(BLK) void k_logm(const float* __restrict__ x,
                                              float* __restrict__ out, Coefs cf) {
  __shared__ __align__(16) float lds[MATS][2][LROW];
  const int lm = threadIdx.x / 24, r = threadIdx.x % 24;
  const long mat = (long)blockIdx.x * MATS + lm;
  float u[24];
  ldrow24(x + mat*576 + (long)r*24, u);
  const float invd = cf.c[30], cd = cf.c[31];
#pragma unroll
  for (int j = 0; j < 24; ++j) u[j] *= invd;
  u[r] -= cd;
  strow24(&lds[lm][0][r*24], u);
  __syncthreads();
  float u2[24], u3[24], u4[24];
#pragma unroll
  for (int j = 0; j < 24; ++j) { u2[j] = 0.f; u3[j] = 0.f; u4[j] = 0.f; }
  mm24(u,  lds[lm][0], u2);
  mm24(u2, lds[lm][0], u3);
  mm24(u3, lds[lm][0], u4);
  strow24(&lds[lm][1][r*24], u4);
  __syncthreads();
  float P[24];
#pragma unroll
  for (int j = 0; j < 24; ++j)
    P[j] = cf.c[25]*u[j] + cf.c[26]*u2[j] + cf.c[27]*u3[j];
  P[r] += cf.c[24];
#pragma unroll
  for (int jb = 5; jb >= 0; --jb) {
    float acc[24];
#pragma unroll
    for (int j = 0; j < 24; ++j)
      acc[j] = cf.c[4*jb+1]*u[j] + cf.c[4*jb+2]*u2[j] + cf.c[4*jb+3]*u3[j];
    acc[r] += cf.c[4*jb];
    mm24(P, lds[lm][1], acc);
#pragma unroll
    for (int j = 0; j < 24; ++j) P[j] = acc[j];
  }
  gout:
  strow24(out + mat*576 + (long)r*24, P);
}

// ---------- K2: in-place graph aggregation, one block per (n,m,t) group ----------
__global__ __launch_bounds__(256) void k_agg(const float* __restrict__ A,
                                             float* __restrict__ io) {
  __shared__ __align__(16) float Lg[25*576];
  __shared__ float Ag[625];
  const int g = blockIdx.x;
  const float* Lbase = io + (long)g * 25 * 576;
  for (int i = threadIdx.x; i < 25*576/4; i += 256)
    ((float4*)Lg)[i] = ((const float4*)Lbase)[i];
  for (int i = threadIdx.x; i < 625; i += 256)
    Ag[i] = A[(long)g*625 + i];
  __syncthreads();
  for (int rr = threadIdx.x; rr < 600; rr += 256) {
    int j = rr / 24, r = rr % 24;
    float acc[24];
#pragma unroll
    for (int q = 0; q < 24; ++q) acc[q] = 0.f;
    for (int v = 0; v < 25; ++v) {
      float a = Ag[v*25 + j];
      const float* Lr = &Lg[v*576 + r*24];
#pragma unroll
      for (int q = 0; q < 24; ++q) acc[q] += a * Lr[q];
    }
    strow24(io + ((long)g*25 + j)*576 + (long)r*24, acc);
  }
}

// ---------- K3: expm via degree-14 Chebyshev->monomial, PS k=3, in place ----------
__global__ __launch_bounds__(BLK) void k_expm(float* __restrict__ io, Coefs cf) {
  __shared__ __align__(16) float lds[MATS][2][LROW];
  const int lm = threadIdx.x / 24, r = threadIdx.x % 24;
  const long mat = (long)blockIdx.x * MATS + lm;
  float u[24];
  ldrow24(io + mat*576 + (long)r*24, u);
  const float invd = cf.c[30], cd = cf.c[31];
#pragma unroll
  for (int j = 0; j < 24; ++j) u[j] *= invd;
  u[r] -= cd;
  strow24(&lds[lm][0][r*24], u);
  __syncthreads();
  float u2[24], u3[24];
#pragma unroll
  for (int j = 0; j < 24; ++j) { u2[j] = 0.f; u3[j] = 0.f; }
  mm24(u,  lds[lm][0], u2);
  mm24(u2, lds[lm][0], u3);
  strow24(&lds[lm][1][r*24], u3);
  __syncthreads();
  float P[24];
#pragma unroll
  for (int j = 0; j < 24; ++j) P[j] = cf.c[13]*u[j] + cf.c[14]*u2[j];
  P[r] += cf.c[12];
#pragma unroll
  for (int jb = 3; jb >= 0; --jb) {
    float acc[24];
#pragma unroll
    for (int j = 0; j < 24; ++j)
      acc[j] = cf.c[3*jb+1]*u[j] + cf.c[3*jb+2]*u2[j];
    acc[r] += cf.c[3*jb];
    mm24(P, lds[lm][1], acc);
#pragma unroll
    for (int j = 0; j < 24; ++j) P[j] = acc[j];
  }
  strow24(io + mat*576 + (long)r*24, P);
}

// ---------- K4: congruence W X W^T, Frobenius normalize, tuned Newton-Schulz sqrt ----------
__global__ __launch_bounds__(BLK) void k_csqrt(float* __restrict__ io,
                                               const float* __restrict__ W) {
  __shared__ __align__(16) float lds[MATS][2][LROW];
  __shared__ __align__(16) float Wt[576];
  __shared__ float red[BLK];
  const int lm = threadIdx.x / 24, r = threadIdx.x % 24;
  const long mat = (long)blockIdx.x * MATS + lm;
  // transpose of W in LDS (B-operand for C = F * W^T)
  for (int i = threadIdx.x; i < 576; i += BLK) {
    int k = i / 24, j = i % 24;
    Wt[i] = W[j*24 + k];
  }
  float tmp[24];
  ldrow24(io + mat*576 + (long)r*24, tmp);
  strow24(&lds[lm][0][r*24], tmp);
  float wrow[24];
  ldrow24(W + r*24, wrow);
  __syncthreads();
  float frow[24], crow[24];
#pragma unroll
  for (int j = 0; j < 24; ++j) { frow[j] = 0.f; crow[j] = 0.f; }
  mm24(wrow, lds[lm][0], frow);   // F = W * E
  mm24(frow, Wt, crow);           // C = F * W^T
  float s = 0.f;
#pragma unroll
  for (int j = 0; j < 24; ++j) s += crow[j]*crow[j];
  red[threadIdx.x] = s;
  __syncthreads();
  float tot = 0.f;
#pragma unroll
  for (int q = 0; q < 24; ++q) tot += red[lm*24 + q];
  const float inv = 1.0f / sqrtf(tot);
  float Mrow[24], Yrow[24];
#pragma unroll
  for (int j = 0; j < 24; ++j) { Mrow[j] = crow[j]*inv; Yrow[j] = Mrow[j]; }
  // coupled Newton-Schulz with tuned slopes: T = a*I - (a-1)*M
  // Y <- Y*T ; M <- M*T^2.  Y converges to sqrt(C/||C||_F).
#pragma unroll 1
  for (int it = 0; it < 10; ++it) {
    const float a = (it < 6) ? 2.0f : 1.5f;
    const float am1 = a - 1.0f;
    float trow[24];
#pragma unroll
    for (int j = 0; j < 24; ++j) trow[j] = -am1 * Mrow[j];
    trow[r] += a;
    strow24(&lds[lm][0][r*24], trow);
    __syncthreads();
    if (it < 9) {
      float yacc[24], t2[24];
#pragma unroll
      for (int j = 0; j < 24; ++j) { yacc[j] = 0.f; t2[j] = 0.f; }
      mm24_dual(Yrow, trow, lds[lm][0], yacc, t2);   // Y*T and T*T
#pragma unroll
      for (int j = 0; j < 24; ++j) Yrow[j] = yacc[j];
      strow24(&lds[lm][1][r*24], t2);
      __syncthreads();
      float macc[24];
#pragma unroll
      for (int j = 0; j < 24; ++j) macc[j] = 0.f;
      mm24(Mrow, lds[lm][1], macc);                  // M*T^2
#pragma unroll
      for (int j = 0; j < 24; ++j) Mrow[j] = macc[j];
    } else {
      float yacc[24];
#pragma unroll
      for (int j = 0; j < 24; ++j) yacc[j] = 0.f;
      mm24(Yrow, lds[lm][0], yacc);
#pragma unroll
      for (int j = 0; j < 24; ++j) Yrow[j] = yacc[j];
    }
  }
  strow24(io + mat*576 + (long)r*24, Yrow);
}

// ---------- host: Chebyshev interpolation -> monomial coefficients in u ----------
static void chebfit_host(double lo, double hi, int D, int islog, float* out) {
  const int N = 200;
  double a[32];
  for (int k = 0; k < 32; ++k) a[k] = 0.0;
  for (int i = 0; i < N; ++i) {
    double th = M_PI * (i + 0.5) / N;
    double u = cos(th);
    double xx = 0.5 * ((hi - lo) * u + (hi + lo));
    double f = islog ? log(xx) : exp(xx);
    for (int k = 0; k <= D; ++k) a[k] += f * cos(k * th);
  }
  for (int k = 0; k <= D; ++k) a[k] *= 2.0 / N;
  a[0] *= 0.5;
  double b[32], tp[32], tc[32], tn[32];
  for (int m = 0; m < 32; ++m) { b[m] = 0; tp[m] = 0; tc[m] = 0; tn[m] = 0; }
  tp[0] = 1.0; b[0] += a[0];
  tc[1] = 1.0; if (D >= 1) b[1] += a[1];
  for (int k = 2; k <= D; ++k) {
    for (int m = 0; m < 32; ++m) tn[m] = -tp[m];
    for (int m = 1; m < 32; ++m) tn[m] += 2.0 * tc[m-1];
    for (int m = 0; m <= k; ++m) b[m] += a[k] * tn[m];
    for (int m = 0; m < 32; ++m) { tp[m] = tc[m]; tc[m] = tn[m]; }
  }
  for (int m = 0; m < 32; ++m) out[m] = (float)b[m];
  out[30] = (float)(2.0 / (hi - lo));          // 1/d
  out[31] = (float)((hi + lo) / (hi - lo));    // c/d
}

extern "C" void kernel_launch(void* const* d_in, const int* in_sizes, int n_in,
                              void* d_out, int out_size, void* d_ws, size_t ws_size,
                              hipStream_t stream) {
  const float* x = (const float*)d_in[0];
  const float* A = (const float*)d_in[1];
  const float* W = (const float*)d_in[2];
  float* out = (float*)d_out;

  Coefs cl, ce;
  chebfit_host(0.47, 7.9, 27, 1, cl.c);   // log on the SPD input spectrum
  chebfit_host(-1.8, 3.9, 14, 0, ce.c);   // exp on the aggregated tangent spectrum

  k_logm <<<NMATS/MATS, BLK, 0, stream>>>(x, out, cl);
  k_agg  <<<NGROUPS,   256, 0, stream>>>(A, out);
  k_expm <<<NMATS/MATS, BLK, 0, stream>>>(out, ce);
  k_csqrt<<<NMATS/MATS, BLK, 0, stream>>>(out, W);
}

// Round 2
// 2801.344 us; speedup vs baseline: 1.9689x; 1.9689x over previous
//
#include <hip/hip_runtime.h>
#include <math.h>

#ifndef M_PI
#define M_PI 3.14159265358979323846
#endif

#define MATS 8
#define BLK 192           // MATS*24
#define NMATS 38400
#define NGROUPS 1536
#define LROW 588          // buffer stride in floats (576 + 12 for bank stagger)

static_assert(BLK == MATS * 24, "block = MATS*24");

struct Coefs { float c[32]; };

// ---------- row helpers ----------
__device__ __forceinline__ void ldrow24(const float* p, float* r) {
  const float4* q = (const float4*)p;
#pragma unroll
  for (int i = 0; i < 6; ++i) {
    float4 v = q[i];
    r[4*i+0] = v.x; r[4*i+1] = v.y; r[4*i+2] = v.z; r[4*i+3] = v.w;
  }
}
__device__ __forceinline__ void strow24(float* p, const float* r) {
  float4* q = (float4*)p;
#pragma unroll
  for (int i = 0; i < 6; ++i)
    q[i] = make_float4(r[4*i+0], r[4*i+1], r[4*i+2], r[4*i+3]);
}

// acc[j] += sum_k arow[k] * B[k*24+j]   (B in LDS, rows broadcast across the
// 24 lanes of a matrix; matrices bank-staggered so <=3 distinct addrs/wave
// hit disjoint banks)
__device__ __forceinline__ void mm24(const float* __restrict__ arow,
                                     const float* __restrict__ B,
                                     float* __restrict__ acc) {
#pragma unroll
  for (int k = 0; k < 24; ++k) {
    float b[24];
    ldrow24(B + k*24, b);
    const float a = arow[k];
#pragma unroll
    for (int j = 0; j < 24; ++j) acc[j] += a * b[j];
  }
}
// two A-rows against the same B (shares the LDS row loads)
__device__ __forceinline__ void mm24_dual(const float* __restrict__ a1,
                                          const float* __restrict__ a2,
                                          const float* __restrict__ B,
                                          float* __restrict__ acc1,
                                          float* __restrict__ acc2) {
#pragma unroll
  for (int k = 0; k < 24; ++k) {
    float b[24];
    ldrow24(B + k*24, b);
    const float s1 = a1[k], s2 = a2[k];
#pragma unroll
    for (int j = 0; j < 24; ++j) { acc1[j] += s1 * b[j]; acc2[j] += s2 * b[j]; }
  }
}

// ---------- K1: logm, degree-23 Chebyshev->monomial, Paterson-Stockmeyer k=4
// live set: u(24) + P(24) + acc(24) + b(24) = 96 floats. Powers u2,u3,u4 in LDS.
__global__ __launch_bounds__(BLK) void k_logm(const float* __restrict__ x,
                                              float* __restrict__ out, Coefs cf) {
  __shared__ __align__(16) float lds[MATS][3][LROW];   // 56448 B
  const int lm = threadIdx.x / 24, r = threadIdx.x % 24;
  const long mat = (long)blockIdx.x * MATS + lm;
  float* L0 = lds[lm][0];   // u, later u4
  float* L1 = lds[lm][1];   // u2
  float* L2 = lds[lm][2];   // u3
  float u[24];
  ldrow24(x + mat*576 + (long)r*24, u);
  const float invd = cf.c[30], cd = cf.c[31];
#pragma unroll
  for (int j = 0; j < 24; ++j) u[j] *= invd;
  u[r] -= cd;
  strow24(&L0[r*24], u);
  __syncthreads();
  float t[24];
#pragma unroll
  for (int j = 0; j < 24; ++j) t[j] = 0.f;
  mm24(u, L0, t);                       // u2
  strow24(&L1[r*24], t);
  __syncthreads();
  float t2[24];
#pragma unroll
  for (int j = 0; j < 24; ++j) t2[j] = 0.f;
  mm24(t, L0, t2);                      // u3 = u2*u
  strow24(&L2[r*24], t2);
  __syncthreads();
#pragma unroll
  for (int j = 0; j < 24; ++j) t[j] = 0.f;
  mm24(t2, L0, t);                      // u4 = u3*u
  __syncthreads();                      // all reads of L0(=u) done
  strow24(&L0[r*24], t);                // L0 = u4
  __syncthreads();
  // top PS block jb=5: c20 I + c21 u + c22 u2 + c23 u3
  float P[24], b[24];
  ldrow24(&L1[r*24], b);
#pragma unroll
  for (int j = 0; j < 24; ++j) P[j] = cf.c[21]*u[j] + cf.c[22]*b[j];
  ldrow24(&L2[r*24], b);
#pragma unroll
  for (int j = 0; j < 24; ++j) P[j] += cf.c[23]*b[j];
  P[r] += cf.c[20];
#pragma unroll
  for (int jb = 4; jb >= 0; --jb) {
    float acc[24];
    ldrow24(&L1[r*24], b);
#pragma unroll
    for (int j = 0; j < 24; ++j) acc[j] = cf.c[4*jb+1]*u[j] + cf.c[4*jb+2]*b[j];
    ldrow24(&L2[r*24], b);
#pragma unroll
    for (int j = 0; j < 24; ++j) acc[j] += cf.c[4*jb+3]*b[j];
    acc[r] += cf.c[4*jb];
    mm24(P, L0, acc);                   // acc += P*u4
#pragma unroll
    for (int j = 0; j < 24; ++j) P[j] = acc[j];
  }
  strow24(out + mat*576 + (long)r*24, P);
}

// ---------- K2: graph aggregation, one block per (n,m,t) group.
// thread -> (r = rr/25, j = rr%25): lanes with equal r broadcast the same LDS row.
__global__ __launch_bounds__(256) void k_agg(const float* __restrict__ A,
                                             float* __restrict__ io) {
  __shared__ __align__(16) float Lg[25*576];
  __shared__ float Ag[625];
  const int g = blockIdx.x;
  const float* Lbase = io + (long)g * 25 * 576;
  for (int i = threadIdx.x; i < 25*576/4; i += 256)
    ((float4*)Lg)[i] = ((const float4*)Lbase)[i];
  for (int i = threadIdx.x; i < 625; i += 256)
    Ag[i] = A[(long)g*625 + i];
  __syncthreads();
  for (int rr = threadIdx.x; rr < 600; rr += 256) {
    const int r = rr / 25, j = rr % 25;
    float acc[24];
#pragma unroll
    for (int q = 0; q < 24; ++q) acc[q] = 0.f;
#pragma unroll 1
    for (int v = 0; v < 25; ++v) {
      const float a = Ag[v*25 + j];
      float b[24];
      ldrow24(&Lg[v*576 + r*24], b);
#pragma unroll
      for (int q = 0; q < 24; ++q) acc[q] += a * b[q];
    }
    strow24(io + ((long)g*25 + j)*576 + (long)r*24, acc);
  }
}

// ---------- K3: expm, degree-11 Chebyshev->monomial, PS k=3, in place.
// live set: u + P + acc + b = 96 floats. u2,u3 in LDS.
__global__ __launch_bounds__(BLK) void k_expm(float* __restrict__ io, Coefs cf) {
  __shared__ __align__(16) float lds[MATS][2][LROW];   // 37632 B
  const int lm = threadIdx.x / 24, r = threadIdx.x % 24;
  const long mat = (long)blockIdx.x * MATS + lm;
  float* L0 = lds[lm][0];   // u, later u3
  float* L1 = lds[lm][1];   // u2
  float u[24];
  ldrow24(io + mat*576 + (long)r*24, u);
  const float invd = cf.c[30], cd = cf.c[31];
#pragma unroll
  for (int j = 0; j < 24; ++j) u[j] *= invd;
  u[r] -= cd;
  strow24(&L0[r*24], u);
  __syncthreads();
  float t[24];
#pragma unroll
  for (int j = 0; j < 24; ++j) t[j] = 0.f;
  mm24(u, L0, t);                       // u2
  strow24(&L1[r*24], t);
  __syncthreads();
  float t2[24];
#pragma unroll
  for (int j = 0; j < 24; ++j) t2[j] = 0.f;
  mm24(t, L0, t2);                      // u3 = u2*u
  __syncthreads();                      // all reads of L0(=u) done
  strow24(&L0[r*24], t2);               // L0 = u3
  __syncthreads();
  // top PS block jb=3: c9 I + c10 u + c11 u2
  float P[24], b[24];
  ldrow24(&L1[r*24], b);
#pragma unroll
  for (int j = 0; j < 24; ++j) P[j] = cf.c[10]*u[j] + cf.c[11]*b[j];
  P[r] += cf.c[9];
#pragma unroll
  for (int jb = 2; jb >= 0; --jb) {
    float acc[24];
    ldrow24(&L1[r*24], b);
#pragma unroll
    for (int j = 0; j < 24; ++j) acc[j] = cf.c[3*jb+1]*u[j] + cf.c[3*jb+2]*b[j];
    acc[r] += cf.c[3*jb];
    mm24(P, L0, acc);                   // acc += P*u3
#pragma unroll
    for (int j = 0; j < 24; ++j) P[j] = acc[j];
  }
  strow24(io + mat*576 + (long)r*24, P);
}

// ---------- K4: congruence W X W^T, Frobenius normalize, 9-step Newton-Schulz sqrt.
// T kept in LDS; per-iter: mm_dual(Y,M;T) then mm(MT;T) -> 3 matmuls sharing B.
__global__ __launch_bounds__(BLK) void k_csqrt(float* __restrict__ io,
                                               const float* __restrict__ W) {
  __shared__ __align__(16) float lds[MATS][LROW];      // 18816 B
  __shared__ __align__(16) float Wt[576];
  __shared__ float red[BLK];
  const int lm = threadIdx.x / 24, r = threadIdx.x % 24;
  const long mat = (long)blockIdx.x * MATS + lm;
  float* L0 = lds[lm];
  for (int i = threadIdx.x; i < 576; i += BLK) {
    const int k = i / 24, j = i % 24;
    Wt[i] = W[j*24 + k];
  }
  {
    float e[24];
    ldrow24(io + mat*576 + (long)r*24, e);
    strow24(&L0[r*24], e);
  }
  float wrow[24];
  ldrow24(W + (long)r*24, wrow);
  __syncthreads();
  float f[24];
#pragma unroll
  for (int j = 0; j < 24; ++j) f[j] = 0.f;
  mm24(wrow, L0, f);                    // F = W * E
  float c[24];
#pragma unroll
  for (int j = 0; j < 24; ++j) c[j] = 0.f;
  mm24(f, Wt, c);                       // C = F * W^T
  float s = 0.f;
#pragma unroll
  for (int j = 0; j < 24; ++j) s += c[j]*c[j];
  red[threadIdx.x] = s;
  __syncthreads();
  float tot = 0.f;
#pragma unroll
  for (int q = 0; q < 24; ++q) tot += red[lm*24 + q];
  const float inv = 1.0f / sqrtf(tot);
  float M[24], Y[24];
#pragma unroll
  for (int j = 0; j < 24; ++j) { M[j] = c[j]*inv; Y[j] = M[j]; }
#pragma unroll 1
  for (int it = 0; it < 9; ++it) {
    const float a   = (it < 6) ? 2.0f : 1.5f;
    const float am1 = a - 1.0f;
    float t[24];
#pragma unroll
    for (int j = 0; j < 24; ++j) t[j] = -am1 * M[j];
    t[r] += a;
    __syncthreads();                    // all reads of previous L0 done
    strow24(&L0[r*24], t);
    __syncthreads();                    // T visible
    if (it < 8) {
      float y2[24], mt[24];
#pragma unroll
      for (int j = 0; j < 24; ++j) { y2[j] = 0.f; mt[j] = 0.f; }
      mm24_dual(Y, M, L0, y2, mt);      // Y*T, M*T (shared B reads)
#pragma unroll
      for (int j = 0; j < 24; ++j) Y[j] = y2[j];
      float m2[24];
#pragma unroll
      for (int j = 0; j < 24; ++j) m2[j] = 0.f;
      mm24(mt, L0, m2);                 // (M*T)*T
#pragma unroll
      for (int j = 0; j < 24; ++j) M[j] = m2[j];
    } else {
      float y2[24];
#pragma unroll
      for (int j = 0; j < 24; ++j) y2[j] = 0.f;
      mm24(Y, L0, y2);                  // final Y*T only
#pragma unroll
      for (int j = 0; j < 24; ++j) Y[j] = y2[j];
    }
  }
  strow24(io + mat*576 + (long)r*24, Y);
}

// ---------- host: Chebyshev interpolation -> monomial coefficients in u ----------
static void chebfit_host(double lo, double hi, int D, int islog, float* out) {
  const int N = 200;
  double a[32];
  for (int k = 0; k < 32; ++k) a[k] = 0.0;
  for (int i = 0; i < N; ++i) {
    double th = M_PI * (i + 0.5) / N;
    double u = cos(th);
    double xx = 0.5 * ((hi - lo) * u + (hi + lo));
    double f = islog ? log(xx) : exp(xx);
    for (int k = 0; k <= D; ++k) a[k] += f * cos(k * th);
  }
  for (int k = 0; k <= D; ++k) a[k] *= 2.0 / N;
  a[0] *= 0.5;
  double b[32], tp[32], tc[32], tn[32];
  for (int m = 0; m < 32; ++m) { b[m] = 0; tp[m] = 0; tc[m] = 0; tn[m] = 0; }
  tp[0] = 1.0; b[0] += a[0];
  tc[1] = 1.0; if (D >= 1) b[1] += a[1];
  for (int k = 2; k <= D; ++k) {
    for (int m = 0; m < 32; ++m) tn[m] = -tp[m];
    for (int m = 1; m < 32; ++m) tn[m] += 2.0 * tc[m-1];
    for (int m = 0; m <= k; ++m) b[m] += a[k] * tn[m];
    for (int m = 0; m < 32; ++m) { tp[m] = tc[m]; tc[m] = tn[m]; }
  }
  for (int m = 0; m < 32; ++m) out[m] = (float)b[m];
  out[30] = (float)(2.0 / (hi - lo));          // 1/d
  out[31] = (float)((hi + lo) / (hi - lo));    // c/d
}

extern "C" void kernel_launch(void* const* d_in, const int* in_sizes, int n_in,
                              void* d_out, int out_size, void* d_ws, size_t ws_size,
                              hipStream_t stream) {
  const float* x = (const float*)d_in[0];
  const float* A = (const float*)d_in[1];
  const float* W = (const float*)d_in[2];
  float* out = (float*)d_out;

  Coefs cl, ce;
  chebfit_host(0.47, 7.9, 23, 1, cl.c);   // log on the SPD input spectrum
  chebfit_host(-1.8, 3.9, 11, 0, ce.c);   // exp on the aggregated tangent spectrum

  k_logm <<<NMATS/MATS, BLK, 0, stream>>>(x, out, cl);
  k_agg  <<<NGROUPS,   256, 0, stream>>>(A, out);
  k_expm <<<NMATS/MATS, BLK, 0, stream>>>(out, ce);
  k_csqrt<<<NMATS/MATS, BLK, 0, stream>>>(out, W);
}

// Round 3
// 1189.130 us; speedup vs baseline: 4.6383x; 2.3558x over previous
//
#include <hip/hip_runtime.h>
#include <math.h>

#ifndef M_PI
#define M_PI 3.14159265358979323846
#endif

#define MATS 8
#define BLK 192           // MATS*24 threads; thread tile = 2 rows x 12 cols
#define NMATS 38400
#define NGROUPS 1536
#define LROW 588          // per-buffer stride in floats (24*24 + 12)

static_assert(BLK == MATS * 24, "block = MATS*24");

struct Coefs { float c[32]; };

// ---------- vector helpers (all fully unrolled; no dynamic reg indexing) ----------
__device__ __forceinline__ void ld12(const float* p, float* r) {
  const float4* q = (const float4*)p;
#pragma unroll
  for (int i = 0; i < 3; ++i) {
    float4 v = q[i];
    r[4*i+0] = v.x; r[4*i+1] = v.y; r[4*i+2] = v.z; r[4*i+3] = v.w;
  }
}
__device__ __forceinline__ void st12(float* p, const float* r) {
  float4* q = (float4*)p;
#pragma unroll
  for (int i = 0; i < 3; ++i)
    q[i] = make_float4(r[4*i+0], r[4*i+1], r[4*i+2], r[4*i+3]);
}
__device__ __forceinline__ void ld24(const float* p, float* r) {
  const float4* q = (const float4*)p;
#pragma unroll
  for (int i = 0; i < 6; ++i) {
    float4 v = q[i];
    r[4*i+0] = v.x; r[4*i+1] = v.y; r[4*i+2] = v.z; r[4*i+3] = v.w;
  }
}
__device__ __forceinline__ void zero12(float* r) {
#pragma unroll
  for (int j = 0; j < 12; ++j) r[j] = 0.f;
}
// += c on the diagonal elements that land in this thread's 2x12 tile
__device__ __forceinline__ void add_diag(float* t0, float* t1, int p, int h, float c) {
#pragma unroll
  for (int j = 0; j < 12; ++j) {
    t0[j] += (h == 0 && j == p) ? c : 0.f;
    t1[j] += (h == 1 && j == p) ? c : 0.f;
  }
}

// acc{0,1}[j] += sum_k a{0,1}[k] * B[k*24 + j], j over this thread's 12-col slice.
// B points at (LDS buffer + c0). k-loop fully unrolled so a0[k]/a1[k] are static;
// sched_barrier every 6 steps bounds load hoisting (<=18 ds_reads in flight).
__device__ __forceinline__ void mmtile(const float* __restrict__ a0,
                                       const float* __restrict__ a1,
                                       const float* __restrict__ B,
                                       float* __restrict__ acc0,
                                       float* __restrict__ acc1) {
#pragma unroll
  for (int k = 0; k < 24; ++k) {
    float b[12];
    ld12(B + k*24, b);
    const float x0 = a0[k], x1 = a1[k];
#pragma unroll
    for (int j = 0; j < 12; ++j) { acc0[j] += x0 * b[j]; acc1[j] += x1 * b[j]; }
    if ((k % 6) == 5) __builtin_amdgcn_sched_barrier(0);
  }
}

// ---------- K1: logm, degree-23 Chebyshev->monomial, PS k=4 ----------
__global__ __launch_bounds__(BLK) void k_logm(const float* __restrict__ x,
                                              float* __restrict__ out, Coefs cf) {
  __shared__ __align__(16) float lds[MATS][4][LROW];   // 75264 B -> 2 blocks/CU
  const int tid = threadIdx.x;
  const int lm = tid / 24, t24 = tid % 24, p = t24 >> 1, h = t24 & 1, c0 = h * 12;
  const long mat = (long)blockIdx.x * MATS + lm;
  float *L0 = lds[lm][0], *L1 = lds[lm][1], *L2 = lds[lm][2], *L3 = lds[lm][3];
  const float invd = cf.c[30], cd = cf.c[31];

  float u0[12], u1[12];
  ld12(x + mat*576 + p*24 + c0, u0);
  ld12(x + mat*576 + (p+12)*24 + c0, u1);
#pragma unroll
  for (int j = 0; j < 12; ++j) { u0[j] *= invd; u1[j] *= invd; }
  add_diag(u0, u1, p, h, -cd);
  st12(&L0[p*24 + c0], u0); st12(&L0[(p+12)*24 + c0], u1);
  __syncthreads();

  float a0[24], a1[24], t0[12], t1[12];
  // u2 -> L1
  ld24(&L0[p*24], a0); ld24(&L0[(p+12)*24], a1);
  zero12(t0); zero12(t1);
  mmtile(a0, a1, L0 + c0, t0, t1);
  st12(&L1[p*24 + c0], t0); st12(&L1[(p+12)*24 + c0], t1);
  __syncthreads();
  // u3 -> L2
  ld24(&L1[p*24], a0); ld24(&L1[(p+12)*24], a1);
  zero12(t0); zero12(t1);
  mmtile(a0, a1, L0 + c0, t0, t1);
  st12(&L2[p*24 + c0], t0); st12(&L2[(p+12)*24 + c0], t1);
  __syncthreads();
  // u4 -> (regs), then overwrite L0
  ld24(&L2[p*24], a0); ld24(&L2[(p+12)*24], a1);
  zero12(t0); zero12(t1);
  mmtile(a0, a1, L0 + c0, t0, t1);
  __syncthreads();                       // all reads of L0(=u) done
  st12(&L0[p*24 + c0], t0); st12(&L0[(p+12)*24 + c0], t1);
  __syncthreads();                       // L0 = u4 visible

  // top PS block jb=5: c20 I + c21 u + c22 u2 + c23 u3
  float P0[12], P1[12], w0[12], w1[12];
  ld12(&L1[p*24 + c0], w0); ld12(&L1[(p+12)*24 + c0], w1);
#pragma unroll
  for (int j = 0; j < 12; ++j) {
    P0[j] = cf.c[21]*u0[j] + cf.c[22]*w0[j];
    P1[j] = cf.c[21]*u1[j] + cf.c[22]*w1[j];
  }
  ld12(&L2[p*24 + c0], w0); ld12(&L2[(p+12)*24 + c0], w1);
#pragma unroll
  for (int j = 0; j < 12; ++j) { P0[j] += cf.c[23]*w0[j]; P1[j] += cf.c[23]*w1[j]; }
  add_diag(P0, P1, p, h, cf.c[20]);

#pragma unroll 1
  for (int jb = 4; jb >= 0; --jb) {
    st12(&L3[p*24 + c0], P0); st12(&L3[(p+12)*24 + c0], P1);
    __syncthreads();
    float acc0[12], acc1[12];
    ld12(&L1[p*24 + c0], w0); ld12(&L1[(p+12)*24 + c0], w1);
#pragma unroll
    for (int j = 0; j < 12; ++j) {
      acc0[j] = cf.c[4*jb+1]*u0[j] + cf.c[4*jb+2]*w0[j];
      acc1[j] = cf.c[4*jb+1]*u1[j] + cf.c[4*jb+2]*w1[j];
    }
    ld12(&L2[p*24 + c0], w0); ld12(&L2[(p+12)*24 + c0], w1);
#pragma unroll
    for (int j = 0; j < 12; ++j) { acc0[j] += cf.c[4*jb+3]*w0[j]; acc1[j] += cf.c[4*jb+3]*w1[j]; }
    add_diag(acc0, acc1, p, h, cf.c[4*jb]);
    ld24(&L3[p*24], a0); ld24(&L3[(p+12)*24], a1);
    mmtile(a0, a1, L0 + c0, acc0, acc1);   // += P * u4
#pragma unroll
    for (int j = 0; j < 12; ++j) { P0[j] = acc0[j]; P1[j] = acc1[j]; }
    __syncthreads();                       // L3 reads done before next overwrite
  }
  st12(out + mat*576 + p*24 + c0, P0);
  st12(out + mat*576 + (p+12)*24 + c0, P1);
}

// ---------- K2: graph aggregation (unchanged structure) ----------
__global__ __launch_bounds__(256) void k_agg(const float* __restrict__ A,
                                             float* __restrict__ io) {
  __shared__ __align__(16) float Lg[25*576];
  __shared__ float Ag[625];
  const int g = blockIdx.x;
  const float* Lbase = io + (long)g * 25 * 576;
  for (int i = threadIdx.x; i < 25*576/4; i += 256)
    ((float4*)Lg)[i] = ((const float4*)Lbase)[i];
  for (int i = threadIdx.x; i < 625; i += 256)
    Ag[i] = A[(long)g*625 + i];
  __syncthreads();
  for (int rr = threadIdx.x; rr < 600; rr += 256) {
    const int r = rr / 25, j = rr % 25;
    float acc[24];
#pragma unroll
    for (int q = 0; q < 24; ++q) acc[q] = 0.f;
#pragma unroll 1
    for (int v = 0; v < 25; ++v) {
      const float a = Ag[v*25 + j];
      float b[24];
      ld24(&Lg[v*576 + r*24], b);
#pragma unroll
      for (int q = 0; q < 24; ++q) acc[q] += a * b[q];
    }
    float* dst = io + ((long)g*25 + j)*576 + (long)r*24;
    float4* qd = (float4*)dst;
#pragma unroll
    for (int i = 0; i < 6; ++i)
      qd[i] = make_float4(acc[4*i], acc[4*i+1], acc[4*i+2], acc[4*i+3]);
  }
}

// ---------- K3: expm, degree-11 Chebyshev->monomial, PS k=3, in place ----------
__global__ __launch_bounds__(BLK) void k_expm(float* __restrict__ io, Coefs cf) {
  __shared__ __align__(16) float lds[MATS][3][LROW];   // 56448 B
  const int tid = threadIdx.x;
  const int lm = tid / 24, t24 = tid % 24, p = t24 >> 1, h = t24 & 1, c0 = h * 12;
  const long mat = (long)blockIdx.x * MATS + lm;
  float *L0 = lds[lm][0], *L1 = lds[lm][1], *L2 = lds[lm][2];
  const float invd = cf.c[30], cd = cf.c[31];

  float u0[12], u1[12];
  ld12(io + mat*576 + p*24 + c0, u0);
  ld12(io + mat*576 + (p+12)*24 + c0, u1);
#pragma unroll
  for (int j = 0; j < 12; ++j) { u0[j] *= invd; u1[j] *= invd; }
  add_diag(u0, u1, p, h, -cd);
  st12(&L0[p*24 + c0], u0); st12(&L0[(p+12)*24 + c0], u1);
  __syncthreads();

  float a0[24], a1[24], t0[12], t1[12];
  // u2 -> L1
  ld24(&L0[p*24], a0); ld24(&L0[(p+12)*24], a1);
  zero12(t0); zero12(t1);
  mmtile(a0, a1, L0 + c0, t0, t1);
  st12(&L1[p*24 + c0], t0); st12(&L1[(p+12)*24 + c0], t1);
  __syncthreads();
  // u3 -> regs, overwrite L0
  ld24(&L1[p*24], a0); ld24(&L1[(p+12)*24], a1);
  zero12(t0); zero12(t1);
  mmtile(a0, a1, L0 + c0, t0, t1);
  __syncthreads();
  st12(&L0[p*24 + c0], t0); st12(&L0[(p+12)*24 + c0], t1);
  __syncthreads();                       // L0 = u3

  float w0[12], w1[12];
  ld12(&L1[p*24 + c0], w0); ld12(&L1[(p+12)*24 + c0], w1);   // u2 tiles (persistent)
  float P0[12], P1[12];
#pragma unroll
  for (int j = 0; j < 12; ++j) {
    P0[j] = cf.c[10]*u0[j] + cf.c[11]*w0[j];
    P1[j] = cf.c[10]*u1[j] + cf.c[11]*w1[j];
  }
  add_diag(P0, P1, p, h, cf.c[9]);

#pragma unroll 1
  for (int jb = 2; jb >= 0; --jb) {
    st12(&L2[p*24 + c0], P0); st12(&L2[(p+12)*24 + c0], P1);
    __syncthreads();
    float acc0[12], acc1[12];
#pragma unroll
    for (int j = 0; j < 12; ++j) {
      acc0[j] = cf.c[3*jb+1]*u0[j] + cf.c[3*jb+2]*w0[j];
      acc1[j] = cf.c[3*jb+1]*u1[j] + cf.c[3*jb+2]*w1[j];
    }
    add_diag(acc0, acc1, p, h, cf.c[3*jb]);
    ld24(&L2[p*24], a0); ld24(&L2[(p+12)*24], a1);
    mmtile(a0, a1, L0 + c0, acc0, acc1);   // += P * u3
#pragma unroll
    for (int j = 0; j < 12; ++j) { P0[j] = acc0[j]; P1[j] = acc1[j]; }
    __syncthreads();
  }
  st12(io + mat*576 + p*24 + c0, P0);
  st12(io + mat*576 + (p+12)*24 + c0, P1);
}

// ---------- K4: congruence + Frobenius norm + 9-step Newton-Schulz sqrt ----------
// NS reformulated so B-operand is always plain M:  Y*T = a*Y - (a-1)*(Y*M), etc.
__global__ __launch_bounds__(BLK) void k_csqrt(float* __restrict__ io,
                                               const float* __restrict__ W) {
  __shared__ __align__(16) float lds[MATS][3][LROW];   // LY, LM, LT = 56448 B
  __shared__ __align__(16) float Wt[576];
  __shared__ float red[BLK];
  const int tid = threadIdx.x;
  const int lm = tid / 24, t24 = tid % 24, p = t24 >> 1, h = t24 & 1, c0 = h * 12;
  const long mat = (long)blockIdx.x * MATS + lm;
  float *LY = lds[lm][0], *LM = lds[lm][1], *LT = lds[lm][2];

  for (int i = tid; i < 576; i += BLK) {
    const int k = i / 24, j = i % 24;
    Wt[i] = W[j*24 + k];
  }
  {
    float e0[12], e1[12];
    ld12(io + mat*576 + p*24 + c0, e0);
    ld12(io + mat*576 + (p+12)*24 + c0, e1);
    st12(&LY[p*24 + c0], e0); st12(&LY[(p+12)*24 + c0], e1);
  }
  float a0[24], a1[24];
  ld24(W + p*24, a0); ld24(W + (p+12)*24, a1);    // W rows (A-operand)
  __syncthreads();

  float t0[12], t1[12];
  zero12(t0); zero12(t1);
  mmtile(a0, a1, LY + c0, t0, t1);                // F = W * E
  st12(&LM[p*24 + c0], t0); st12(&LM[(p+12)*24 + c0], t1);
  __syncthreads();

  float ct0[12], ct1[12];
  zero12(ct0); zero12(ct1);
  ld24(&LM[p*24], a0); ld24(&LM[(p+12)*24], a1);
  mmtile(a0, a1, Wt + c0, ct0, ct1);              // C = F * W^T
  float s = 0.f;
#pragma unroll
  for (int j = 0; j < 12; ++j) s += ct0[j]*ct0[j] + ct1[j]*ct1[j];
  red[tid] = s;
  __syncthreads();
  float tot = 0.f;
#pragma unroll
  for (int q = 0; q < 24; ++q) tot += red[lm*24 + q];
  const float inv = 1.0f / sqrtf(tot);

  float Y0[12], Y1[12], M0[12], M1[12];
#pragma unroll
  for (int j = 0; j < 12; ++j) {
    M0[j] = ct0[j]*inv; M1[j] = ct1[j]*inv;
  }
  __syncthreads();                                // LM(F) reads done
  st12(&LM[p*24 + c0], M0); st12(&LM[(p+12)*24 + c0], M1);
  __syncthreads();                                // LM = M0 (normalized)

  // ---- iter 0 (a=2, Y=M): Y1 = M*T = 2M - M*M ; M1 = (M*T)*T
  {
    float mm0[12], mm1[12];
    zero12(mm0); zero12(mm1);
    ld24(&LM[p*24], a0); ld24(&LM[(p+12)*24], a1);
    mmtile(a0, a1, LM + c0, mm0, mm1);            // M*M
#pragma unroll
    for (int j = 0; j < 12; ++j) {
      Y0[j] = 2.f*M0[j] - mm0[j];                 // MT tiles (= new Y)
      Y1[j] = 2.f*M1[j] - mm1[j];
    }
    __syncthreads();
    st12(&LT[p*24 + c0], Y0); st12(&LT[(p+12)*24 + c0], Y1);
    st12(&LY[p*24 + c0], Y0); st12(&LY[(p+12)*24 + c0], Y1);
    __syncthreads();
    float q0[12], q1[12];
    zero12(q0); zero12(q1);
    ld24(&LT[p*24], a0); ld24(&LT[(p+12)*24], a1);
    mmtile(a0, a1, LM + c0, q0, q1);              // (MT)*M
#pragma unroll
    for (int j = 0; j < 12; ++j) {
      M0[j] = 2.f*Y0[j] - q0[j];                  // newM = 2*MT - MT*M
      M1[j] = 2.f*Y1[j] - q1[j];
    }
    __syncthreads();
    st12(&LM[p*24 + c0], M0); st12(&LM[(p+12)*24 + c0], M1);
    __syncthreads();
  }

  // ---- iters 1..7
#pragma unroll 1
  for (int it = 1; it < 8; ++it) {
    const float aa = (it < 6) ? 2.0f : 1.5f;
    const float am1 = aa - 1.0f;
    float ym0[12], ym1[12];
    zero12(ym0); zero12(ym1);
    ld24(&LY[p*24], a0); ld24(&LY[(p+12)*24], a1);
    mmtile(a0, a1, LM + c0, ym0, ym1);            // Y*M
    float mm0[12], mm1[12];
    zero12(mm0); zero12(mm1);
    ld24(&LM[p*24], a0); ld24(&LM[(p+12)*24], a1);
    mmtile(a0, a1, LM + c0, mm0, mm1);            // M*M
#pragma unroll
    for (int j = 0; j < 12; ++j) {
      Y0[j] = aa*Y0[j] - am1*ym0[j];              // newY = Y*T
      Y1[j] = aa*Y1[j] - am1*ym1[j];
      mm0[j] = aa*M0[j] - am1*mm0[j];             // MT = M*T
      mm1[j] = aa*M1[j] - am1*mm1[j];
    }
    __syncthreads();                              // LY/LM reads done
    st12(&LY[p*24 + c0], Y0); st12(&LY[(p+12)*24 + c0], Y1);
    st12(&LT[p*24 + c0], mm0); st12(&LT[(p+12)*24 + c0], mm1);
    __syncthreads();
    float q0[12], q1[12];
    zero12(q0); zero12(q1);
    ld24(&LT[p*24], a0); ld24(&LT[(p+12)*24], a1);
    mmtile(a0, a1, LM + c0, q0, q1);              // (MT)*M
#pragma unroll
    for (int j = 0; j < 12; ++j) {
      M0[j] = aa*mm0[j] - am1*q0[j];              // newM = MT*T
      M1[j] = aa*mm1[j] - am1*q1[j];
    }
    __syncthreads();
    st12(&LM[p*24 + c0], M0); st12(&LM[(p+12)*24 + c0], M1);
    __syncthreads();
  }

  // ---- iter 8 (a=1.5): final Y = 1.5*Y - 0.5*(Y*M)
  {
    float ym0[12], ym1[12];
    zero12(ym0); zero12(ym1);
    ld24(&LY[p*24], a0); ld24(&LY[(p+12)*24], a1);
    mmtile(a0, a1, LM + c0, ym0, ym1);
#pragma unroll
    for (int j = 0; j < 12; ++j) {
      Y0[j] = 1.5f*Y0[j] - 0.5f*ym0[j];
      Y1[j] = 1.5f*Y1[j] - 0.5f*ym1[j];
    }
  }
  st12(io + mat*576 + p*24 + c0, Y0);
  st12(io + mat*576 + (p+12)*24 + c0, Y1);
}

// ---------- host: Chebyshev interpolation -> monomial coefficients in u ----------
static void chebfit_host(double lo, double hi, int D, int islog, float* out) {
  const int N = 200;
  double a[32];
  for (int k = 0; k < 32; ++k) a[k] = 0.0;
  for (int i = 0; i < N; ++i) {
    double th = M_PI * (i + 0.5) / N;
    double u = cos(th);
    double xx = 0.5 * ((hi - lo) * u + (hi + lo));
    double f = islog ? log(xx) : exp(xx);
    for (int k = 0; k <= D; ++k) a[k] += f * cos(k * th);
  }
  for (int k = 0; k <= D; ++k) a[k] *= 2.0 / N;
  a[0] *= 0.5;
  double b[32], tp[32], tc[32], tn[32];
  for (int m = 0; m < 32; ++m) { b[m] = 0; tp[m] = 0; tc[m] = 0; tn[m] = 0; }
  tp[0] = 1.0; b[0] += a[0];
  tc[1] = 1.0; if (D >= 1) b[1] += a[1];
  for (int k = 2; k <= D; ++k) {
    for (int m = 0; m < 32; ++m) tn[m] = -tp[m];
    for (int m = 1; m < 32; ++m) tn[m] += 2.0 * tc[m-1];
    for (int m = 0; m <= k; ++m) b[m] += a[k] * tn[m];
    for (int m = 0; m < 32; ++m) { tp[m] = tc[m]; tc[m] = tn[m]; }
  }
  for (int m = 0; m < 32; ++m) out[m] = (float)b[m];
  out[30] = (float)(2.0 / (hi - lo));          // 1/d
  out[31] = (float)((hi + lo) / (hi - lo));    // c/d
}

extern "C" void kernel_launch(void* const* d_in, const int* in_sizes, int n_in,
                              void* d_out, int out_size, void* d_ws, size_t ws_size,
                              hipStream_t stream) {
  const float* x = (const float*)d_in[0];
  const float* A = (const float*)d_in[1];
  const float* W = (const float*)d_in[2];
  float* out = (float*)d_out;

  Coefs cl, ce;
  chebfit_host(0.47, 7.9, 23, 1, cl.c);   // log on the SPD input spectrum
  chebfit_host(-1.8, 3.9, 11, 0, ce.c);   // exp on the aggregated tangent spectrum

  k_logm <<<NMATS/MATS, BLK, 0, stream>>>(x, out, cl);
  k_agg  <<<NGROUPS,   256, 0, stream>>>(A, out);
  k_expm <<<NMATS/MATS, BLK, 0, stream>>>(out, ce);
  k_csqrt<<<NMATS/MATS, BLK, 0, stream>>>(out, W);
}